// Round 2
// baseline (331.688 us; speedup 1.0000x reference)
//
#include <hip/hip_runtime.h>

#define B_SZ 32
#define C_CH 64
#define D_TOT 16000
#define N_CHUNK 25
#define CHUNK 640      // 5 iterations * 128
#define TILE_D 128

// ws layout: [B][64*64] Gram (upper triangle filled) then [B][64] channel sums
#define WS_G_ELEMS (B_SZ * C_CH * C_CH)
#define WS_S_ELEMS (B_SZ * C_CH)

__global__ __launch_bounds__(256) void gram_partial(
    const float* __restrict__ x, float* __restrict__ wsG, float* __restrict__ wsS)
{
    __shared__ float tile[TILE_D * C_CH];  // 32 KB, c-major rows of 128 floats, XOR-swizzled
    const int t = threadIdx.x;
    const int b = blockIdx.y;
    const int chunk = blockIdx.x;
    const int w  = t >> 6;      // wave id 0..3
    const int l  = t & 63;      // lane
    const int tr = l >> 3;      // thread row in 8x8 grid
    const int tc = l & 7;       // thread col
    const int cld = t >> 2;     // channel this thread loads (0..63)
    const int q   = t & 3;      // quarter within channel

    const float* xb = x + (size_t)b * C_CH * D_TOT;

    float acc[8][8];
    #pragma unroll
    for (int i = 0; i < 8; ++i)
        #pragma unroll
        for (int k = 0; k < 8; ++k) acc[i][k] = 0.0f;

    float ssum = 0.0f;
    const int swzL = (cld & 56) >> 1;  // ((c>>3)&7)*4, load-side swizzle
    const int trs = tr * 4;            // compute-side swizzle for c-fragment
    const int tcs = tc * 4;            // compute-side swizzle for e-fragment

    for (int it = 0; it < 5; ++it) {
        const int dbase = chunk * CHUNK + it * TILE_D;
        // ---- global -> LDS: 128 d x 64 c ----
        const float* src = xb + (size_t)cld * D_TOT + dbase;
        #pragma unroll
        for (int j = 0; j < 8; ++j) {
            const int d = q * 4 + j * 16;
            float4 v = *reinterpret_cast<const float4*>(src + d);
            ssum += v.x + v.y + v.z + v.w;
            const int idx = cld * TILE_D + (d & ~31) + ((d & 31) ^ swzL);
            *reinterpret_cast<float4*>(tile + idx) = v;
        }
        __syncthreads();
        // ---- compute: wave w covers d in [w*32, w*32+32) ----
        const float* tw = tile + w * 32;
        #pragma unroll
        for (int dd = 0; dd < 32; dd += 4) {
            float4 cf[8];
            const int offc = dd ^ trs;
            const int offe = dd ^ tcs;
            #pragma unroll
            for (int i = 0; i < 8; ++i)
                cf[i] = *reinterpret_cast<const float4*>(tw + (tr * 8 + i) * TILE_D + offc);
            #pragma unroll
            for (int k = 0; k < 8; ++k) {
                const float4 ef = *reinterpret_cast<const float4*>(tw + (tc * 8 + k) * TILE_D + offe);
                #pragma unroll
                for (int i = 0; i < 8; ++i) {
                    acc[i][k] += cf[i].x * ef.x;
                    acc[i][k] += cf[i].y * ef.y;
                    acc[i][k] += cf[i].z * ef.z;
                    acc[i][k] += cf[i].w * ef.w;
                }
            }
        }
        __syncthreads();
    }

    // ---- channel sums: 4 loader-threads per channel ----
    ssum += __shfl_xor(ssum, 1);
    ssum += __shfl_xor(ssum, 2);
    if (q == 0) atomicAdd(&wsS[b * C_CH + cld], ssum);

    // ---- cross-wave reduce in LDS (reuse tile). RIDX(c,e) = c*64 + (e ^ (c>>3)) -> 2-way free ----
    float* red = tile;
    if (w == 0) {
        #pragma unroll
        for (int i = 0; i < 8; ++i) {
            const int c = tr * 8 + i;
            #pragma unroll
            for (int k = 0; k < 8; ++k)
                red[c * 64 + ((tc * 8 + k) ^ tr)] = acc[i][k];
        }
    }
    __syncthreads();
    if (w == 1) {
        #pragma unroll
        for (int i = 0; i < 8; ++i) {
            const int c = tr * 8 + i;
            #pragma unroll
            for (int k = 0; k < 8; ++k)
                red[c * 64 + ((tc * 8 + k) ^ tr)] += acc[i][k];
        }
    }
    __syncthreads();
    if (w == 2) {
        #pragma unroll
        for (int i = 0; i < 8; ++i) {
            const int c = tr * 8 + i;
            #pragma unroll
            for (int k = 0; k < 8; ++k)
                red[c * 64 + ((tc * 8 + k) ^ tr)] += acc[i][k];
        }
    }
    __syncthreads();
    if (w == 3) {
        #pragma unroll
        for (int i = 0; i < 8; ++i) {
            const int c = tr * 8 + i;
            #pragma unroll
            for (int k = 0; k < 8; ++k)
                red[c * 64 + ((tc * 8 + k) ^ tr)] += acc[i][k];
        }
    }
    __syncthreads();

    // ---- one atomicAdd per upper-triangle element ----
    float* gOut = wsG + (size_t)b * (C_CH * C_CH);
    #pragma unroll
    for (int m = 0; m < 16; ++m) {
        const int idx = t * 16 + m;
        const int c = idx >> 6;
        const int e = idx & 63;
        if (e >= c)
            atomicAdd(&gOut[idx], red[c * 64 + (e ^ (c >> 3))]);
    }
}

__global__ __launch_bounds__(256) void finalize_kernel(
    const float* __restrict__ wsG, const float* __restrict__ wsS, float* __restrict__ out)
{
    __shared__ float shS[64];
    __shared__ float shStd[64];
    __shared__ float shDeg[64];
    __shared__ float shDsi[64];
    __shared__ float shBin[64][65];
    const int b = blockIdx.x;
    const int t = threadIdx.x;
    const float* G = wsG + (size_t)b * (C_CH * C_CH);

    if (t < 64) {
        const float S = wsS[b * C_CH + t];
        const float gcc = G[t * 64 + t];
        const float mean = S * (1.0f / 16000.0f);
        const float var = (gcc - S * mean) * (1.0f / 15999.0f);  // ddof=1
        shS[t] = S;
        shStd[t] = sqrtf(var) + 1e-8f;
    }
    __syncthreads();

    const int r  = t >> 2;
    const int cb = (t & 3) * 16;
    const float Sc = shS[r];
    const float stdc = shStd[r];
    float deg = 0.0f;
    #pragma unroll
    for (int m = 0; m < 16; ++m) {
        const int e = cb + m;
        const float g = (e >= r) ? G[r * 64 + e] : G[e * 64 + r];
        const float a = (g - Sc * shS[e] * (1.0f / 16000.0f)) / (stdc * shStd[e] * 1000.0f);
        float bin = (a > 0.5f) ? 1.0f : 0.0f;
        if (e == r) bin += 1.0f;
        shBin[r][e] = bin;
        deg += bin;
    }
    deg += __shfl_xor(deg, 1);
    deg += __shfl_xor(deg, 2);
    if ((t & 3) == 0) shDeg[r] = deg;
    __syncthreads();
    if (t < 64) shDsi[t] = 1.0f / sqrtf(shDeg[t] + 1e-8f);
    __syncthreads();

    float* ob = out + (size_t)b * (C_CH * C_CH);
    const float dr = shDsi[r];
    #pragma unroll
    for (int m = 0; m < 16; ++m) {
        const int e = cb + m;
        ob[r * 64 + e] = shBin[r][e] * dr * shDsi[e];
    }
}

extern "C" void kernel_launch(void* const* d_in, const int* in_sizes, int n_in,
                              void* d_out, int out_size, void* d_ws, size_t ws_size,
                              hipStream_t stream)
{
    const float* x = (const float*)d_in[0];
    float* out = (float*)d_out;
    float* wsG = (float*)d_ws;
    float* wsS = (float*)d_ws + WS_G_ELEMS;

    hipMemsetAsync(d_ws, 0, (WS_G_ELEMS + WS_S_ELEMS) * sizeof(float), stream);
    gram_partial<<<dim3(N_CHUNK, B_SZ), 256, 0, stream>>>(x, wsG, wsS);
    finalize_kernel<<<B_SZ, 256, 0, stream>>>(wsG, wsS, out);
}

// Round 3
// 199.586 us; speedup vs baseline: 1.6619x; 1.6619x over previous
//
#include <hip/hip_runtime.h>

#define B_SZ 32
#define C_CH 64
#define D_TOT 16000
#define N_CHUNK 25
#define CHUNK 640
#define KT 128   // k elements per LDS tile
#define NT 5     // tiles per block (5*128 = 640 = CHUNK)

typedef short bf16x8 __attribute__((ext_vector_type(8)));
typedef short short4v __attribute__((ext_vector_type(4)));
typedef float f32x4 __attribute__((ext_vector_type(4)));

#define WS_G_ELEMS (B_SZ * C_CH * C_CH)
#define WS_S_ELEMS (B_SZ * C_CH)

__device__ __forceinline__ short f2bf(float f) {
    // round-to-nearest-even fp32 -> bf16 (no NaN handling; inputs are finite)
    unsigned u = __builtin_bit_cast(unsigned, f);
    u = (u + 0x7FFFu + ((u >> 16) & 1u)) >> 16;
    return (short)u;
}

__global__ __launch_bounds__(256) void gram_mfma(
    const float* __restrict__ x, float* __restrict__ wsG, float* __restrict__ wsS)
{
    // 2 x (64 ch x 128 k) bf16 = 2 x 16 KB, XOR-swizzled: byte ^= (ch&7)<<4
    __shared__ __align__(16) short tile[2][C_CH * KT];

    const int t = threadIdx.x;
    const int b = blockIdx.y;
    const int chunk = blockIdx.x;
    const int l = t & 63;
    const int w = t >> 6;
    const int w0 = (w >> 1) * 32;  // output row base for this wave
    const int w1 = (w & 1) * 32;   // output col base for this wave

    const float* xb = x + (size_t)b * (C_CH * D_TOT) + chunk * CHUNK;

    // ---- loader geometry: thread t, slot j -> channel (t>>5)+8j, d = (t&31)*4 ----
    const int lch = t >> 5;
    const int ldp = (t & 31) * 4;
    const float* rp[8];
    int wb[8];
    #pragma unroll
    for (int j = 0; j < 8; ++j) {
        const int ch = lch + 8 * j;
        rp[j] = xb + (size_t)ch * D_TOT + ldp;
        wb[j] = (ch * 256 + ldp * 2) ^ ((ch & 7) << 4);   // 8B-aligned swizzled byte off
    }

    // ---- fragment geometry (mfma_f32_16x16x32_bf16) ----
    const int fl = l & 15;          // row/col within 16-tile
    const int fg = (l >> 4) * 16;   // byte offset of this lane's 8-elem k-group

    f32x4 acc[2][2];
    #pragma unroll
    for (int i = 0; i < 2; ++i)
        #pragma unroll
        for (int k = 0; k < 2; ++k)
            acc[i][k] = (f32x4){0.f, 0.f, 0.f, 0.f};

    float ssum[8];
    #pragma unroll
    for (int j = 0; j < 8; ++j) ssum[j] = 0.f;

    float4 ld[8];

    // ---- prologue: load + convert + write tile 0 ----
    #pragma unroll
    for (int j = 0; j < 8; ++j) ld[j] = *reinterpret_cast<const float4*>(rp[j]);
    {
        char* buf = (char*)tile[0];
        #pragma unroll
        for (int j = 0; j < 8; ++j) {
            const float4 v = ld[j];
            ssum[j] += v.x + v.y + v.z + v.w;
            short4v s;
            s[0] = f2bf(v.x); s[1] = f2bf(v.y); s[2] = f2bf(v.z); s[3] = f2bf(v.w);
            *reinterpret_cast<short4v*>(buf + wb[j]) = s;
        }
    }
    __syncthreads();

    // ---- main loop: 2-phase double buffer ----
    #pragma unroll
    for (int tt = 0; tt < NT; ++tt) {
        if (tt + 1 < NT) {
            #pragma unroll
            for (int j = 0; j < 8; ++j)
                ld[j] = *reinterpret_cast<const float4*>(rp[j] + (tt + 1) * KT);
        }

        // compute on buf[tt&1]
        {
            const char* buf = (const char*)tile[tt & 1];
            #pragma unroll
            for (int kk = 0; kk < 4; ++kk) {
                const int k64 = kk * 64;
                const int chA0 = w0 + fl,      chA1 = w0 + 16 + fl;
                const int chB0 = w1 + fl,      chB1 = w1 + 16 + fl;
                const bf16x8 a0 = *reinterpret_cast<const bf16x8*>(
                    buf + ((chA0 * 256 + fg + k64) ^ ((chA0 & 7) << 4)));
                const bf16x8 a1 = *reinterpret_cast<const bf16x8*>(
                    buf + ((chA1 * 256 + fg + k64) ^ ((chA1 & 7) << 4)));
                const bf16x8 b0 = *reinterpret_cast<const bf16x8*>(
                    buf + ((chB0 * 256 + fg + k64) ^ ((chB0 & 7) << 4)));
                const bf16x8 b1 = *reinterpret_cast<const bf16x8*>(
                    buf + ((chB1 * 256 + fg + k64) ^ ((chB1 & 7) << 4)));
                acc[0][0] = __builtin_amdgcn_mfma_f32_16x16x32_bf16(a0, b0, acc[0][0], 0, 0, 0);
                acc[0][1] = __builtin_amdgcn_mfma_f32_16x16x32_bf16(a0, b1, acc[0][1], 0, 0, 0);
                acc[1][0] = __builtin_amdgcn_mfma_f32_16x16x32_bf16(a1, b0, acc[1][0], 0, 0, 0);
                acc[1][1] = __builtin_amdgcn_mfma_f32_16x16x32_bf16(a1, b1, acc[1][1], 0, 0, 0);
            }
        }

        if (tt + 1 < NT) {
            char* buf = (char*)tile[(tt + 1) & 1];
            #pragma unroll
            for (int j = 0; j < 8; ++j) {
                const float4 v = ld[j];
                ssum[j] += v.x + v.y + v.z + v.w;
                short4v s;
                s[0] = f2bf(v.x); s[1] = f2bf(v.y); s[2] = f2bf(v.z); s[3] = f2bf(v.w);
                *reinterpret_cast<short4v*>(buf + wb[j]) = s;
            }
        }
        __syncthreads();
    }

    // ---- channel sums: reduce within 32-thread groups, one atomic per (group, j) ----
    #pragma unroll
    for (int j = 0; j < 8; ++j) {
        float v = ssum[j];
        v += __shfl_xor(v, 1);
        v += __shfl_xor(v, 2);
        v += __shfl_xor(v, 4);
        v += __shfl_xor(v, 8);
        v += __shfl_xor(v, 16);
        if ((t & 31) == 0) atomicAdd(&wsS[b * C_CH + lch + 8 * j], v);
    }

    // ---- Gram atomics: full 64x64 (symmetric -> transpose-immune) ----
    float* gOut = wsG + (size_t)b * (C_CH * C_CH);
    const int crow = w0 + ((l >> 4) << 2);
    const int ccol = w1 + fl;
    #pragma unroll
    for (int ct = 0; ct < 2; ++ct)
        #pragma unroll
        for (int tj = 0; tj < 2; ++tj)
            #pragma unroll
            for (int r = 0; r < 4; ++r)
                atomicAdd(&gOut[(crow + ct * 16 + r) * 64 + (ccol + tj * 16)],
                          acc[ct][tj][r]);
}

__global__ __launch_bounds__(256) void finalize_kernel(
    const float* __restrict__ wsG, const float* __restrict__ wsS, float* __restrict__ out)
{
    __shared__ float shS[64];
    __shared__ float shStd[64];
    __shared__ float shDeg[64];
    __shared__ float shDsi[64];
    __shared__ float shBin[64][65];
    const int b = blockIdx.x;
    const int t = threadIdx.x;
    const float* G = wsG + (size_t)b * (C_CH * C_CH);

    if (t < 64) {
        const float S = wsS[b * C_CH + t];
        const float gcc = G[t * 64 + t];
        const float mean = S * (1.0f / 16000.0f);
        const float var = (gcc - S * mean) * (1.0f / 15999.0f);  // ddof=1
        shS[t] = S;
        shStd[t] = sqrtf(var) + 1e-8f;
    }
    __syncthreads();

    const int r  = t >> 2;
    const int cb = (t & 3) * 16;
    const float Sc = shS[r];
    const float stdc = shStd[r];
    float deg = 0.0f;
    #pragma unroll
    for (int m = 0; m < 16; ++m) {
        const int e = cb + m;
        const float g = G[r * 64 + e];   // full matrix is populated now
        const float a = (g - Sc * shS[e] * (1.0f / 16000.0f)) / (stdc * shStd[e] * 1000.0f);
        float bin = (a > 0.5f) ? 1.0f : 0.0f;
        if (e == r) bin += 1.0f;
        shBin[r][e] = bin;
        deg += bin;
    }
    deg += __shfl_xor(deg, 1);
    deg += __shfl_xor(deg, 2);
    if ((t & 3) == 0) shDeg[r] = deg;
    __syncthreads();
    if (t < 64) shDsi[t] = 1.0f / sqrtf(shDeg[t] + 1e-8f);
    __syncthreads();

    float* ob = out + (size_t)b * (C_CH * C_CH);
    const float dr = shDsi[r];
    #pragma unroll
    for (int m = 0; m < 16; ++m) {
        const int e = cb + m;
        ob[r * 64 + e] = shBin[r][e] * dr * shDsi[e];
    }
}

extern "C" void kernel_launch(void* const* d_in, const int* in_sizes, int n_in,
                              void* d_out, int out_size, void* d_ws, size_t ws_size,
                              hipStream_t stream)
{
    const float* x = (const float*)d_in[0];
    float* out = (float*)d_out;
    float* wsG = (float*)d_ws;
    float* wsS = (float*)d_ws + WS_G_ELEMS;

    hipMemsetAsync(d_ws, 0, (WS_G_ELEMS + WS_S_ELEMS) * sizeof(float), stream);
    gram_mfma<<<dim3(N_CHUNK, B_SZ), 256, 0, stream>>>(x, wsG, wsS);
    finalize_kernel<<<B_SZ, 256, 0, stream>>>(wsG, wsS, out);
}

// Round 5
// 198.222 us; speedup vs baseline: 1.6733x; 1.0069x over previous
//
#include <hip/hip_runtime.h>

#define B_SZ 32
#define C_CH 64
#define D_TOT 16000
#define NP 25        // chunks along D
#define CHUNK 640
#define KT 128       // k per LDS tile
#define NT 5         // tiles per chunk

typedef short bf16x8 __attribute__((ext_vector_type(8)));
typedef float f32x4 __attribute__((ext_vector_type(4)));

// ws layout (floats): partG [NP][B][4096] | partS [NP][B][64] | redG [B][4096]
#define PARTG_ELEMS (NP * B_SZ * 4096)
#define PARTS_ELEMS (NP * B_SZ * 64)

__device__ __forceinline__ unsigned f2bf_pk(float a, float b) {
    // round-to-nearest-even fp32 -> bf16, packed pair (inputs finite)
    unsigned ua = __builtin_bit_cast(unsigned, a);
    unsigned ub = __builtin_bit_cast(unsigned, b);
    ua = (ua + 0x7FFFu + ((ua >> 16) & 1u)) >> 16;
    ub = (ub + 0x7FFFu + ((ub >> 16) & 1u)) >> 16;
    return (ua & 0xFFFFu) | (ub << 16);
}

__global__ __launch_bounds__(256) void gram_mfma(
    const float* __restrict__ x, float* __restrict__ partG, float* __restrict__ partS)
{
    __shared__ __align__(16) short tile[2][C_CH * KT];  // 2 x 16 KB, byte ^= (ch&7)<<4

    const int t = threadIdx.x;
    const int b = blockIdx.y;
    const int chunk = blockIdx.x;
    const int l = t & 63;
    const int w = t >> 6;
    const int w0 = (w >> 1) * 32;
    const int w1 = (w & 1) * 32;

    const float* xb = x + (size_t)b * (C_CH * D_TOT) + chunk * CHUNK;

    const int lch = t >> 5;          // loader channel group base
    const int ldp = (t & 31) * 4;    // element offset within tile row
    const float* rp[8];
    int wb[8];
    #pragma unroll
    for (int j = 0; j < 8; ++j) {
        const int ch = lch + 8 * j;
        rp[j] = xb + (size_t)ch * D_TOT + ldp;
        wb[j] = (ch * 256 + ldp * 2) ^ ((ch & 7) << 4);   // swizzled byte offset (8B-aligned)
    }

    const int fl = l & 15;
    const int fg = (l >> 4) * 16;    // byte offset of lane's 8-elem k-group

    f32x4 acc[2][2];
    #pragma unroll
    for (int i = 0; i < 2; ++i)
        #pragma unroll
        for (int k = 0; k < 2; ++k)
            acc[i][k] = (f32x4){0.f, 0.f, 0.f, 0.f};

    float ssum[8];
    #pragma unroll
    for (int j = 0; j < 8; ++j) ssum[j] = 0.f;

    float4 ld[8];

#define CVT_STORE(BUFIDX)                                                        \
    {                                                                            \
        char* buf_ = (char*)tile[BUFIDX];                                        \
        _Pragma("unroll")                                                        \
        for (int j = 0; j < 8; ++j) {                                            \
            const float4 v = ld[j];                                              \
            ssum[j] += v.x + v.y + v.z + v.w;                                    \
            uint2 u;                                                             \
            u.x = f2bf_pk(v.x, v.y);                                             \
            u.y = f2bf_pk(v.z, v.w);                                             \
            *reinterpret_cast<uint2*>(buf_ + wb[j]) = u;                         \
        }                                                                        \
    }

    // ---- prologue: L0 -> buf0, issue L1 ----
    #pragma unroll
    for (int j = 0; j < 8; ++j) ld[j] = *reinterpret_cast<const float4*>(rp[j]);
    CVT_STORE(0)
    #pragma unroll
    for (int j = 0; j < 8; ++j) ld[j] = *reinterpret_cast<const float4*>(rp[j] + KT);
    __syncthreads();

    // ---- pipelined main loop: one barrier per tile ----
    #pragma unroll
    for (int tt = 0; tt < NT; ++tt) {
        if (tt + 1 < NT) {
            CVT_STORE((tt + 1) & 1)               // loads issued 1 full iter ago
            if (tt + 2 < NT) {
                #pragma unroll
                for (int j = 0; j < 8; ++j)
                    ld[j] = *reinterpret_cast<const float4*>(rp[j] + (tt + 2) * KT);
            }
        }
        {
            const char* buf = (const char*)tile[tt & 1];
            #pragma unroll
            for (int kk = 0; kk < 4; ++kk) {
                const int k64 = kk * 64;
                const int chA0 = w0 + fl,      chA1 = w0 + 16 + fl;
                const int chB0 = w1 + fl,      chB1 = w1 + 16 + fl;
                const bf16x8 a0 = *reinterpret_cast<const bf16x8*>(
                    buf + ((chA0 * 256 + fg + k64) ^ ((chA0 & 7) << 4)));
                const bf16x8 a1 = *reinterpret_cast<const bf16x8*>(
                    buf + ((chA1 * 256 + fg + k64) ^ ((chA1 & 7) << 4)));
                const bf16x8 b0 = *reinterpret_cast<const bf16x8*>(
                    buf + ((chB0 * 256 + fg + k64) ^ ((chB0 & 7) << 4)));
                const bf16x8 b1 = *reinterpret_cast<const bf16x8*>(
                    buf + ((chB1 * 256 + fg + k64) ^ ((chB1 & 7) << 4)));
                acc[0][0] = __builtin_amdgcn_mfma_f32_16x16x32_bf16(a0, b0, acc[0][0], 0, 0, 0);
                acc[0][1] = __builtin_amdgcn_mfma_f32_16x16x32_bf16(a0, b1, acc[0][1], 0, 0, 0);
                acc[1][0] = __builtin_amdgcn_mfma_f32_16x16x32_bf16(a1, b0, acc[1][0], 0, 0, 0);
                acc[1][1] = __builtin_amdgcn_mfma_f32_16x16x32_bf16(a1, b1, acc[1][1], 0, 0, 0);
            }
        }
        __syncthreads();
    }
#undef CVT_STORE

    // ---- channel partial sums (no atomics) ----
    const size_t pbase = (size_t)(chunk * B_SZ + b);
    #pragma unroll
    for (int j = 0; j < 8; ++j) {
        float v = ssum[j];
        v += __shfl_xor(v, 1);
        v += __shfl_xor(v, 2);
        v += __shfl_xor(v, 4);
        v += __shfl_xor(v, 8);
        v += __shfl_xor(v, 16);
        if ((t & 31) == 0) partS[pbase * 64 + lch + 8 * j] = v;
    }

    // ---- Gram partial store (no atomics; full 64x64, symmetric) ----
    float* gOut = partG + pbase * 4096;
    const int crow = w0 + ((l >> 4) << 2);
    const int ccol = w1 + fl;
    #pragma unroll
    for (int ct = 0; ct < 2; ++ct)
        #pragma unroll
        for (int tj = 0; tj < 2; ++tj)
            #pragma unroll
            for (int r = 0; r < 4; ++r)
                gOut[(crow + ct * 16 + r) * 64 + (ccol + tj * 16)] = acc[ct][tj][r];
}

__global__ __launch_bounds__(256) void reduce_g(
    const float* __restrict__ partG, float* __restrict__ redG)
{
    const int i = blockIdx.x * 256 + threadIdx.x;   // float4 id, 32768 total
    const int b = i >> 10;                          // 1024 float4 per batch
    const int o = (i & 1023) * 4;
    f32x4 s = (f32x4){0.f, 0.f, 0.f, 0.f};
    #pragma unroll
    for (int c = 0; c < NP; ++c)
        s += *reinterpret_cast<const f32x4*>(partG + ((size_t)(c * B_SZ + b)) * 4096 + o);
    *reinterpret_cast<f32x4*>(redG + (size_t)b * 4096 + o) = s;
}

__global__ __launch_bounds__(256) void finalize_kernel(
    const float* __restrict__ redG, const float* __restrict__ partS, float* __restrict__ out)
{
    __shared__ float shS[64];
    __shared__ float shStd[64];
    __shared__ float shDeg[64];
    __shared__ float shDsi[64];
    __shared__ float shBin[64][65];
    const int b = blockIdx.x;
    const int t = threadIdx.x;
    const float* G = redG + (size_t)b * 4096;

    if (t < 64) {
        float S = 0.f;
        #pragma unroll
        for (int c = 0; c < NP; ++c)
            S += partS[(size_t)(c * B_SZ + b) * 64 + t];
        const float gcc = G[t * 64 + t];
        const float mean = S * (1.0f / 16000.0f);
        const float var = (gcc - S * mean) * (1.0f / 15999.0f);  // ddof=1
        shS[t] = S;
        shStd[t] = sqrtf(var) + 1e-8f;
    }
    __syncthreads();

    const int r  = t >> 2;
    const int cb = (t & 3) * 16;
    const float Sc = shS[r];
    const float stdc = shStd[r];
    float deg = 0.0f;
    #pragma unroll
    for (int m = 0; m < 16; ++m) {
        const int e = cb + m;
        const float g = G[r * 64 + e];
        const float a = (g - Sc * shS[e] * (1.0f / 16000.0f)) / (stdc * shStd[e] * 1000.0f);
        float bin = (a > 0.5f) ? 1.0f : 0.0f;
        if (e == r) bin += 1.0f;
        shBin[r][e] = bin;
        deg += bin;
    }
    deg += __shfl_xor(deg, 1);
    deg += __shfl_xor(deg, 2);
    if ((t & 3) == 0) shDeg[r] = deg;
    __syncthreads();
    if (t < 64) shDsi[t] = 1.0f / sqrtf(shDeg[t] + 1e-8f);
    __syncthreads();

    float* ob = out + (size_t)b * 4096;
    const float dr = shDsi[r];
    #pragma unroll
    for (int m = 0; m < 16; ++m) {
        const int e = cb + m;
        ob[r * 64 + e] = shBin[r][e] * dr * shDsi[e];
    }
}

extern "C" void kernel_launch(void* const* d_in, const int* in_sizes, int n_in,
                              void* d_out, int out_size, void* d_ws, size_t ws_size,
                              hipStream_t stream)
{
    const float* x = (const float*)d_in[0];
    float* out = (float*)d_out;
    float* partG = (float*)d_ws;
    float* partS = partG + PARTG_ELEMS;
    float* redG  = partS + PARTS_ELEMS;

    gram_mfma<<<dim3(NP, B_SZ), 256, 0, stream>>>(x, partG, partS);
    reduce_g<<<128, 256, 0, stream>>>(partG, redG);
    finalize_kernel<<<B_SZ, 256, 0, stream>>>(redG, partS, out);
}

// Round 6
// 197.265 us; speedup vs baseline: 1.6814x; 1.0049x over previous
//
#include <hip/hip_runtime.h>

#define B_SZ 32
#define C_CH 64
#define D_TOT 16000
#define NP 8         // chunks along D -> 256 blocks = 1/CU
#define KT 128       // k per LDS tile; 125 tiles total per batch

typedef short bf16x8 __attribute__((ext_vector_type(8)));
typedef float f32x4 __attribute__((ext_vector_type(4)));

// ws layout (floats): partG [NP][B][4096] | partS [NP][B][64] | redG [B][4096]
#define PARTG_ELEMS (NP * B_SZ * 4096)
#define PARTS_ELEMS (NP * B_SZ * 64)

__device__ __forceinline__ unsigned f2bf_pk(float a, float b) {
    // round-to-nearest-even fp32 -> bf16, packed pair (inputs finite)
    unsigned ua = __builtin_bit_cast(unsigned, a);
    unsigned ub = __builtin_bit_cast(unsigned, b);
    ua = (ua + 0x7FFFu + ((ua >> 16) & 1u)) >> 16;
    ub = (ub + 0x7FFFu + ((ub >> 16) & 1u)) >> 16;
    return (ua & 0xFFFFu) | (ub << 16);
}

__global__ __launch_bounds__(256) void gram_mfma(
    const float* __restrict__ x, float* __restrict__ partG, float* __restrict__ partS)
{
    __shared__ __align__(16) short tile[2][C_CH * KT];  // 2 x 16 KB, byte ^= (ch&7)<<4

    const int t = threadIdx.x;
    const int b = blockIdx.y;
    const int chunk = blockIdx.x;
    // tiles [t0, t0+nt): chunks 0-4 get 16 tiles, 5-7 get 15 (5*16+3*15 = 125)
    const int nt = (chunk < 5) ? 16 : 15;
    const int t0 = (chunk < 5) ? chunk * 16 : 80 + (chunk - 5) * 15;

    const int l = t & 63;
    const int w = t >> 6;
    const int w0 = (w >> 1) * 32;
    const int w1 = (w & 1) * 32;

    const float* xb = x + (size_t)b * (C_CH * D_TOT) + t0 * KT;

    const int lch = t >> 5;          // loader channel group base
    const int ldp = (t & 31) * 4;    // element offset within tile row
    const float* rp[8];
    int wb[8];
    #pragma unroll
    for (int j = 0; j < 8; ++j) {
        const int ch = lch + 8 * j;
        rp[j] = xb + (size_t)ch * D_TOT + ldp;
        wb[j] = (ch * 256 + ldp * 2) ^ ((ch & 7) << 4);   // swizzled byte offset (8B-aligned)
    }

    const int fl = l & 15;
    const int fg = (l >> 4) * 16;    // byte offset of lane's 8-elem k-group

    f32x4 acc[2][2];
    #pragma unroll
    for (int i = 0; i < 2; ++i)
        #pragma unroll
        for (int k = 0; k < 2; ++k)
            acc[i][k] = (f32x4){0.f, 0.f, 0.f, 0.f};

    float ssum[8];
    #pragma unroll
    for (int j = 0; j < 8; ++j) ssum[j] = 0.f;

    float4 ldA[8], ldB[8];

#define ISSUE(SET, TI)                                                           \
    {                                                                            \
        _Pragma("unroll")                                                        \
        for (int j = 0; j < 8; ++j)                                              \
            SET[j] = *reinterpret_cast<const float4*>(rp[j] + (TI) * KT);        \
    }

#define CVT_STORE(SET, BUFIDX)                                                   \
    {                                                                            \
        char* buf_ = (char*)tile[BUFIDX];                                        \
        _Pragma("unroll")                                                        \
        for (int j = 0; j < 8; ++j) {                                            \
            const float4 v = SET[j];                                             \
            ssum[j] += v.x + v.y + v.z + v.w;                                    \
            uint2 u;                                                             \
            u.x = f2bf_pk(v.x, v.y);                                             \
            u.y = f2bf_pk(v.z, v.w);                                             \
            *reinterpret_cast<uint2*>(buf_ + wb[j]) = u;                         \
        }                                                                        \
    }

#define COMPUTE(BUFIDX)                                                          \
    {                                                                            \
        const char* buf = (const char*)tile[BUFIDX];                             \
        _Pragma("unroll")                                                        \
        for (int kk = 0; kk < 4; ++kk) {                                         \
            const int k64 = kk * 64;                                             \
            const int chA0 = w0 + fl,      chA1 = w0 + 16 + fl;                  \
            const int chB0 = w1 + fl,      chB1 = w1 + 16 + fl;                  \
            const bf16x8 a0 = *reinterpret_cast<const bf16x8*>(                  \
                buf + ((chA0 * 256 + fg + k64) ^ ((chA0 & 7) << 4)));            \
            const bf16x8 a1 = *reinterpret_cast<const bf16x8*>(                  \
                buf + ((chA1 * 256 + fg + k64) ^ ((chA1 & 7) << 4)));            \
            const bf16x8 b0 = *reinterpret_cast<const bf16x8*>(                  \
                buf + ((chB0 * 256 + fg + k64) ^ ((chB0 & 7) << 4)));            \
            const bf16x8 b1 = *reinterpret_cast<const bf16x8*>(                  \
                buf + ((chB1 * 256 + fg + k64) ^ ((chB1 & 7) << 4)));            \
            acc[0][0] = __builtin_amdgcn_mfma_f32_16x16x32_bf16(a0, b0, acc[0][0], 0, 0, 0); \
            acc[0][1] = __builtin_amdgcn_mfma_f32_16x16x32_bf16(a0, b1, acc[0][1], 0, 0, 0); \
            acc[1][0] = __builtin_amdgcn_mfma_f32_16x16x32_bf16(a1, b0, acc[1][0], 0, 0, 0); \
            acc[1][1] = __builtin_amdgcn_mfma_f32_16x16x32_bf16(a1, b1, acc[1][1], 0, 0, 0); \
        }                                                                        \
    }

    // ---- prologue: T0->A, T1->B in flight; cvt T0; issue T2->A ----
    ISSUE(ldA, 0)
    ISSUE(ldB, 1)
    CVT_STORE(ldA, 0)
    ISSUE(ldA, 2)
    __syncthreads();

    // ---- main loop: 2 tiles per pass, static register sets, distance-2 issue ----
    for (int tt = 0; tt < nt; tt += 2) {
        // even tile tt: consume odd tile tt+1 from ldB, refill ldB with tt+3
        if (tt + 1 < nt) {
            CVT_STORE(ldB, 1)
            if (tt + 3 < nt) ISSUE(ldB, tt + 3)
        }
        COMPUTE(0)
        __syncthreads();

        // odd tile tt+1: consume even tile tt+2 from ldA, refill ldA with tt+4
        if (tt + 1 < nt) {
            if (tt + 2 < nt) {
                CVT_STORE(ldA, 0)
                if (tt + 4 < nt) ISSUE(ldA, tt + 4)
            }
            COMPUTE(1)
            __syncthreads();
        }
    }
#undef ISSUE
#undef CVT_STORE
#undef COMPUTE

    // ---- channel partial sums (no atomics) ----
    const size_t pbase = (size_t)(chunk * B_SZ + b);
    #pragma unroll
    for (int j = 0; j < 8; ++j) {
        float v = ssum[j];
        v += __shfl_xor(v, 1);
        v += __shfl_xor(v, 2);
        v += __shfl_xor(v, 4);
        v += __shfl_xor(v, 8);
        v += __shfl_xor(v, 16);
        if ((t & 31) == 0) partS[pbase * 64 + lch + 8 * j] = v;
    }

    // ---- Gram partial store (no atomics; full 64x64, symmetric) ----
    float* gOut = partG + pbase * 4096;
    const int crow = w0 + ((l >> 4) << 2);
    const int ccol = w1 + fl;
    #pragma unroll
    for (int ct = 0; ct < 2; ++ct)
        #pragma unroll
        for (int tj = 0; tj < 2; ++tj)
            #pragma unroll
            for (int r = 0; r < 4; ++r)
                gOut[(crow + ct * 16 + r) * 64 + (ccol + tj * 16)] = acc[ct][tj][r];
}

__global__ __launch_bounds__(256) void reduce_g(
    const float* __restrict__ partG, float* __restrict__ redG)
{
    const int i = blockIdx.x * 256 + threadIdx.x;   // float4 id, 32768 total
    const int b = i >> 10;                          // 1024 float4 per batch
    const int o = (i & 1023) * 4;
    f32x4 s = (f32x4){0.f, 0.f, 0.f, 0.f};
    #pragma unroll
    for (int c = 0; c < NP; ++c)
        s += *reinterpret_cast<const f32x4*>(partG + ((size_t)(c * B_SZ + b)) * 4096 + o);
    *reinterpret_cast<f32x4*>(redG + (size_t)b * 4096 + o) = s;
}

__global__ __launch_bounds__(256) void finalize_kernel(
    const float* __restrict__ redG, const float* __restrict__ partS, float* __restrict__ out)
{
    __shared__ float shS[64];
    __shared__ float shStd[64];
    __shared__ float shDeg[64];
    __shared__ float shDsi[64];
    __shared__ float shBin[64][65];
    const int b = blockIdx.x;
    const int t = threadIdx.x;
    const float* G = redG + (size_t)b * 4096;

    if (t < 64) {
        float S = 0.f;
        #pragma unroll
        for (int c = 0; c < NP; ++c)
            S += partS[(size_t)(c * B_SZ + b) * 64 + t];
        const float gcc = G[t * 64 + t];
        const float mean = S * (1.0f / 16000.0f);
        const float var = (gcc - S * mean) * (1.0f / 15999.0f);  // ddof=1
        shS[t] = S;
        shStd[t] = sqrtf(var) + 1e-8f;
    }
    __syncthreads();

    const int r  = t >> 2;
    const int cb = (t & 3) * 16;
    const float Sc = shS[r];
    const float stdc = shStd[r];
    float deg = 0.0f;
    #pragma unroll
    for (int m = 0; m < 16; ++m) {
        const int e = cb + m;
        const float g = G[r * 64 + e];
        const float a = (g - Sc * shS[e] * (1.0f / 16000.0f)) / (stdc * shStd[e] * 1000.0f);
        float bin = (a > 0.5f) ? 1.0f : 0.0f;
        if (e == r) bin += 1.0f;
        shBin[r][e] = bin;
        deg += bin;
    }
    deg += __shfl_xor(deg, 1);
    deg += __shfl_xor(deg, 2);
    if ((t & 3) == 0) shDeg[r] = deg;
    __syncthreads();
    if (t < 64) shDsi[t] = 1.0f / sqrtf(shDeg[t] + 1e-8f);
    __syncthreads();

    float* ob = out + (size_t)b * 4096;
    const float dr = shDsi[r];
    #pragma unroll
    for (int m = 0; m < 16; ++m) {
        const int e = cb + m;
        ob[r * 64 + e] = shBin[r][e] * dr * shDsi[e];
    }
}

extern "C" void kernel_launch(void* const* d_in, const int* in_sizes, int n_in,
                              void* d_out, int out_size, void* d_ws, size_t ws_size,
                              hipStream_t stream)
{
    const float* x = (const float*)d_in[0];
    float* out = (float*)d_out;
    float* partG = (float*)d_ws;
    float* partS = partG + PARTG_ELEMS;
    float* redG  = partS + PARTS_ELEMS;

    gram_mfma<<<dim3(NP, B_SZ), 256, 0, stream>>>(x, partG, partS);
    reduce_g<<<128, 256, 0, stream>>>(partG, redG);
    finalize_kernel<<<B_SZ, 256, 0, stream>>>(redG, partS, out);
}